// Round 4
// baseline (469.808 us; speedup 1.0000x reference)
//
#include <hip/hip_runtime.h>

// Problem constants (from reference setup_inputs)
#define B_  4
#define H_  64
#define W_  64
#define C_  16
#define F_  32
#define PH  66   // padded height
#define PW  66   // padded width

// Padded input, zero borders: [B][PH][PW][C]  (~1.1 MB)
__device__ float g_xpad[B_ * PH * PW * C_];
// Base-orientation weights (P4 via patch permutation):
// layout [cc(8)][tk(2)][p(9)][f(32)][c2(2)]; tk0 = times (slope), tk1 = plus (offset)
__device__ float g_wpk[8 * 2 * 9 * F_ * 2];

#define NW (8 * 2 * 9 * F_)          // 4608 weight float2 entries
#define NX (B_ * PH * PW * 4)        // 69696 float4 pad chunks

// ---- prep: repack weights + zero-pad x (one launch) ----
__global__ void mtp_prep(const float* __restrict__ x,
                         const float* __restrict__ kern,
                         const float* __restrict__ tker) {
    int idx = blockIdx.x * 256 + threadIdx.x;
    if (idx < NW) {
        int f = idx & 31;
        int t = idx >> 5;
        int p = t % 9;  t /= 9;
        int tk = t & 1;
        int cc = t >> 1;
        const float* src = tk ? kern : tker;
        float2 v;
        v.x = src[(p * C_ + cc * 2 + 0) * F_ + f];
        v.y = src[(p * C_ + cc * 2 + 1) * F_ + f];
        *reinterpret_cast<float2*>(g_wpk + idx * 2) = v;
        return;
    }
    int xi = idx - NW;
    if (xi < NX) {
        int cc  = xi & 3;
        int t   = xi >> 2;
        int col = t % PW;  t /= PW;
        int row = t % PH;
        int b   = t / PH;
        float4 v = make_float4(0.f, 0.f, 0.f, 0.f);
        if (row >= 1 && row <= H_ && col >= 1 && col <= W_)
            v = *reinterpret_cast<const float4*>(
                    x + ((b * H_ + row - 1) * W_ + col - 1) * C_ + cc * 4);
        *reinterpret_cast<float4*>(g_xpad + xi * 4) = v;
    }
}

// One channel-pair's working set: 18 weight float2 + 15 x-halo float2 = 66 VGPRs
struct Batch {
    float2 wt[9], wk[9];
    float2 xh[3][5];
};

__device__ __forceinline__ void load_batch(Batch& Bt, const int cc, const int f,
                                           const float* rp0, const float* rp1,
                                           const float* rp2) {
    const float* wtb = g_wpk + ((cc * 2 + 0) * 9 * F_ + f) * 2;
    const float* wkb = g_wpk + ((cc * 2 + 1) * 9 * F_ + f) * 2;
    #pragma unroll
    for (int p = 0; p < 9; ++p) {
        Bt.wt[p] = *reinterpret_cast<const float2*>(wtb + p * F_ * 2);
        Bt.wk[p] = *reinterpret_cast<const float2*>(wkb + p * F_ * 2);
    }
    #pragma unroll
    for (int lc = 0; lc < 5; ++lc) {
        Bt.xh[0][lc] = *reinterpret_cast<const float2*>(rp0 + lc * C_ + cc * 2);
        Bt.xh[1][lc] = *reinterpret_cast<const float2*>(rp1 + lc * C_ + cc * 2);
        Bt.xh[2][lc] = *reinterpret_cast<const float2*>(rp2 + lc * C_ + cc * 2);
    }
}

__device__ __forceinline__ void compute_batch(const Batch& Bt, float acc[4][2]) {
    #pragma unroll
    for (int it = 0; it < 2; ++it) {
        #pragma unroll
        for (int r = 0; r < 4; ++r) {
            float z0[9], z1[9];
            #pragma unroll
            for (int q = 0; q < 9; ++q) {
                const int a = q / 3, bq = q % 3;
                int di, dj;
                switch (r) {   // x position = rot_r^{-1}(weight position q)
                    case 0:  di = a;      dj = bq;     break;
                    case 1:  di = 2 - bq; dj = a;      break;
                    case 2:  di = 2 - a;  dj = 2 - bq; break;
                    default: di = bq;     dj = 2 - a;  break;
                }
                const float2 xv = Bt.xh[di][it * 2 + dj];
                z0[q] = fmaf(xv.x, Bt.wt[q].x, Bt.wk[q].x);
                z1[q] = fmaf(xv.y, Bt.wt[q].y, Bt.wk[q].y);
            }
            float m0 = fmaxf(fmaxf(fmaxf(z0[0], z0[1]), z0[2]),
                       fmaxf(fmaxf(fmaxf(z0[3], z0[4]), z0[5]),
                             fmaxf(fmaxf(z0[6], z0[7]), z0[8])));
            float m1 = fmaxf(fmaxf(fmaxf(z1[0], z1[1]), z1[2]),
                       fmaxf(fmaxf(fmaxf(z1[3], z1[4]), z1[5]),
                             fmaxf(fmaxf(z1[6], z1[7]), z1[8])));
            acc[r][it] += m0 + m1;
        }
    }
}

// ---- main: wave = (b, i, 4-pixel strip), all 4 rotations; lane = (ps, f).
// Explicit 2-deep register double-buffer: 33 loads per batch stay in flight
// while the other batch computes (448 cyc compute > ~300 cyc L2 latency).
__global__ __launch_bounds__(256, 2) void mtp_main(float* __restrict__ out) {
    const int lane = threadIdx.x & 63;
    const int f    = lane & 31;
    const int ps   = lane >> 5;
    const int wid  = (blockIdx.x << 2) + (threadIdx.x >> 6);   // 0..4095
    const int jq   = wid & 15;
    const int i    = (wid >> 4) & 63;
    const int b    = wid >> 10;
    const int jb   = jq << 2;

    const float* rp0 = g_xpad + ((b * PH + i) * PW + jb + ps) * C_;
    const float* rp1 = rp0 + PW * C_;
    const float* rp2 = rp0 + 2 * PW * C_;

    float acc[4][2];
    #pragma unroll
    for (int r = 0; r < 4; ++r) { acc[r][0] = 0.f; acc[r][1] = 0.f; }

    Batch A, Bb;
    load_batch(A,  0, f, rp0, rp1, rp2);
    load_batch(Bb, 1, f, rp0, rp1, rp2);

    #pragma unroll
    for (int cc = 0; cc < 8; cc += 2) {
        compute_batch(A, acc);
        if (cc + 2 < 8) load_batch(A, cc + 2, f, rp0, rp1, rp2);
        compute_batch(Bb, acc);
        if (cc + 3 < 8) load_batch(Bb, cc + 3, f, rp0, rp1, rp2);
    }

    // out[b, r, i, jb+ps+it*2, f]
    #pragma unroll
    for (int r = 0; r < 4; ++r) {
        float* op = out + ((((b * 4 + r) * H_ + i) * W_ + jb + ps) * F_ + f);
        op[0]      = acc[r][0];
        op[2 * F_] = acc[r][1];
    }
}

extern "C" void kernel_launch(void* const* d_in, const int* in_sizes, int n_in,
                              void* d_out, int out_size, void* d_ws, size_t ws_size,
                              hipStream_t stream) {
    const float* x    = (const float*)d_in[0];
    const float* kern = (const float*)d_in[1];
    const float* tker = (const float*)d_in[2];
    float* out = (float*)d_out;

    hipLaunchKernelGGL(mtp_prep, dim3((NW + NX + 255) / 256), dim3(256), 0, stream,
                       x, kern, tker);
    hipLaunchKernelGGL(mtp_main, dim3(1024), dim3(256), 0, stream, out);
}

// Round 5
// 19.195 us; speedup vs baseline: 24.4751x; 24.4751x over previous
//
#include <hip/hip_runtime.h>

// Problem constants (from reference setup_inputs)
#define B_  4
#define H_  64
#define W_  64
#define C_  16
#define F_  32

// Block: 512 threads = 8 waves; covers (b, row i, half-row of 32 pixels).
// Wave w: 4-pixel strip jb_l = w*4 within the half. Lane = (ps 0/1, f 0..31).
// All 4 P4 rotations computed from one patch via compile-time permutation
// (max is permutation-invariant; verified in rounds 2-4).
//
// LDS: weights [cc(8)][q(9)][f(32)] float4 (t_c0,t_c1,k_c0,k_c1)  = 36864 B
//      x halo  [3 rows][34 cols][8 float2-ch]                      =  6528 B
#define NWE (8 * 9 * F_)   // 2304 weight float4 entries
#define NXE (3 * 34 * 4)   // 408 x float4 chunks

__global__ __launch_bounds__(512, 4) void mtp_main(const float* __restrict__ x,
                                                   const float* __restrict__ kern,
                                                   const float* __restrict__ tker,
                                                   float* __restrict__ out) {
    __shared__ float4 wlds[NWE];
    __shared__ float2 xlds[3][34][8];

    const int tid  = threadIdx.x;
    const int bidx = blockIdx.x;                 // (b*64 + i)*2 + half
    const int half = bidx & 1;
    const int i    = (bidx >> 1) & 63;
    const int b    = bidx >> 7;

    // ---- stage weights: gather base-orientation (t,k) pairs into float4 ----
    for (int e = tid; e < NWE; e += 512) {
        int f  = e & 31;
        int t  = e >> 5;                         // cc*9 + q
        int q  = t % 9;
        int cc = t / 9;
        int s0 = (q * C_ + cc * 2 + 0) * F_ + f;
        int s1 = (q * C_ + cc * 2 + 1) * F_ + f;
        wlds[e] = make_float4(tker[s0], tker[s1], kern[s0], kern[s1]);
    }
    // ---- stage x halo (zero-padded): rows i-1..i+1, cols half*32-1 .. +32 ----
    for (int e = tid; e < NXE; e += 512) {
        int cc4 = e & 3;
        int t   = e >> 2;
        int cl  = t % 34;                        // local padded col
        int di  = t / 34;
        int ro  = i + di - 1;
        int co  = half * 32 + cl - 1;
        float4 v = make_float4(0.f, 0.f, 0.f, 0.f);
        if (ro >= 0 && ro < H_ && co >= 0 && co < W_)
            v = *reinterpret_cast<const float4*>(
                    x + ((b * H_ + ro) * W_ + co) * C_ + cc4 * 4);
        *reinterpret_cast<float4*>(&xlds[di][cl][cc4 * 2]) = v;
    }
    __syncthreads();

    const int lane = tid & 63;
    const int f    = lane & 31;
    const int ps   = lane >> 5;
    const int w    = tid >> 6;                   // wave 0..7
    const int jb_l = w << 2;                     // strip base (local col)

    float acc[4][2];
    #pragma unroll
    for (int r = 0; r < 4; ++r) { acc[r][0] = 0.f; acc[r][1] = 0.f; }

    #pragma unroll 1
    for (int cc = 0; cc < 8; ++cc) {
        // weight batch: 9 ds_read_b128, lanes 0-31 consecutive 16B (conflict-free)
        float4 wq[9];
        #pragma unroll
        for (int q = 0; q < 9; ++q)
            wq[q] = wlds[(cc * 9 + q) * F_ + f];
        // x halo batch: 15 ds_read_b64, 2 distinct addrs/wave (broadcast)
        float2 xh[3][5];
        #pragma unroll
        for (int di = 0; di < 3; ++di)
            #pragma unroll
            for (int lc = 0; lc < 5; ++lc)
                xh[di][lc] = xlds[di][jb_l + ps + lc][cc];

        #pragma unroll
        for (int it = 0; it < 2; ++it) {
            #pragma unroll
            for (int r = 0; r < 4; ++r) {
                float z0[9], z1[9];
                #pragma unroll
                for (int q = 0; q < 9; ++q) {
                    const int a = q / 3, bq = q % 3;
                    int di, dj;
                    switch (r) {   // x position = rot_r^{-1}(weight position q)
                        case 0:  di = a;      dj = bq;     break;
                        case 1:  di = 2 - bq; dj = a;      break;
                        case 2:  di = 2 - a;  dj = 2 - bq; break;
                        default: di = bq;     dj = 2 - a;  break;
                    }
                    const float2 xv = xh[di][it * 2 + dj];
                    z0[q] = fmaf(xv.x, wq[q].x, wq[q].z);
                    z1[q] = fmaf(xv.y, wq[q].y, wq[q].w);
                }
                float m0 = fmaxf(fmaxf(fmaxf(z0[0], z0[1]), z0[2]),
                           fmaxf(fmaxf(fmaxf(z0[3], z0[4]), z0[5]),
                                 fmaxf(fmaxf(z0[6], z0[7]), z0[8])));
                float m1 = fmaxf(fmaxf(fmaxf(z1[0], z1[1]), z1[2]),
                           fmaxf(fmaxf(fmaxf(z1[3], z1[4]), z1[5]),
                                 fmaxf(fmaxf(z1[6], z1[7]), z1[8])));
                acc[r][it] += m0 + m1;
            }
        }
    }

    // out[b, r, i, j, f] with j = half*32 + jb_l + it*2 + ps
    const int jg = half * 32 + jb_l + ps;
    #pragma unroll
    for (int r = 0; r < 4; ++r) {
        float* op = out + ((((b * 4 + r) * H_ + i) * W_ + jg) * F_ + f);
        op[0]      = acc[r][0];
        op[2 * F_] = acc[r][1];
    }
}

extern "C" void kernel_launch(void* const* d_in, const int* in_sizes, int n_in,
                              void* d_out, int out_size, void* d_ws, size_t ws_size,
                              hipStream_t stream) {
    const float* x    = (const float*)d_in[0];
    const float* kern = (const float*)d_in[1];
    const float* tker = (const float*)d_in[2];
    float* out = (float*)d_out;

    hipLaunchKernelGGL(mtp_main, dim3(B_ * H_ * 2), dim3(512), 0, stream,
                       x, kern, tker, out);
}